// Round 2
// baseline (4091.525 us; speedup 1.0000x reference)
//
#include <hip/hip_runtime.h>
#include <hip/hip_bf16.h>
#include <cstdint>
#include <cstddef>

// GAT on MI355X. Round 2: split-bf16 MFMA GEMMs + LDS-staged sparse attention.
// T=32 frames, N=512 nodes, Fh=256, H=8 heads, L=3 layers.

typedef short s16x8 __attribute__((ext_vector_type(8)));
typedef float f32x4 __attribute__((ext_vector_type(4)));

__device__ __forceinline__ void async_copy16(const void* g, void* l) {
    __builtin_amdgcn_global_load_lds(
        (const __attribute__((address_space(1))) void*)g,
        (__attribute__((address_space(3))) void*)l, 16, 0, 0);
}

// ---------------- CSR build (ballot compaction, one wave per row) ------------
__global__ __launch_bounds__(256)
void build_csr_kernel(const int* __restrict__ adj, int* __restrict__ cnt,
                      int* __restrict__ idxout)
{
    int row  = blockIdx.x * 4 + (threadIdx.x >> 6);
    int lane = threadIdx.x & 63;
    if (row >= 512) return;
    int base = 0;
    for (int j0 = 0; j0 < 512; j0 += 64) {
        int j = j0 + lane;
        bool pred = adj[row * 512 + j] > 0;
        unsigned long long m = __ballot(pred);
        if (pred) {
            int pos = __popcll(m & ((1ull << lane) - 1ull));
            idxout[row * 512 + base + pos] = j;
        }
        base += __popcll(m);
    }
    if (lane == 0) cnt[row] = base;
}

// ---------------- weight transpose + hi/lo bf16 split ------------------------
// in: [B][K][N] fp32  ->  oh/ol: [B][N][K] bf16
__global__ __launch_bounds__(256)
void transpose_split_kernel(const float* __restrict__ in,
                            __hip_bfloat16* __restrict__ oh,
                            __hip_bfloat16* __restrict__ ol, int K, int N)
{
    int b = blockIdx.z;
    int k0 = blockIdx.y * 32, n0 = blockIdx.x * 32;
    __shared__ float tile[32][33];
    int tx = threadIdx.x & 31, ty = threadIdx.x >> 5;   // 8 rows per pass
    const float* inb = in + (size_t)b * K * N;
    #pragma unroll
    for (int r = 0; r < 32; r += 8)
        tile[ty + r][tx] = inb[(size_t)(k0 + ty + r) * N + n0 + tx];
    __syncthreads();
    __hip_bfloat16* ohb = oh + (size_t)b * K * N;
    __hip_bfloat16* olb = ol + (size_t)b * K * N;
    #pragma unroll
    for (int r = 0; r < 32; r += 8) {
        float v = tile[tx][ty + r];
        __hip_bfloat16 h = __float2bfloat16(v);
        float lo = v - __bfloat162float(h);
        ohb[(size_t)(n0 + ty + r) * K + k0 + tx] = h;
        olb[(size_t)(n0 + ty + r) * K + k0 + tx] = __float2bfloat16(lo);
    }
}

// ---------------- fp32 -> bf16 hi/lo split (row-major, same layout) ----------
__global__ __launch_bounds__(256)
void split_kernel(const float* __restrict__ x, __hip_bfloat16* __restrict__ hi,
                  __hip_bfloat16* __restrict__ lo, int n)
{
    int i = blockIdx.x * 256 + threadIdx.x;
    if (i < n) {
        float v = x[i];
        __hip_bfloat16 h = __float2bfloat16(v);
        hi[i] = h;
        lo[i] = __float2bfloat16(v - __bfloat162float(h));
    }
}

// ---------------- naive fp32 GEMM (only for the K=3 input projection) --------
__global__ __launch_bounds__(256)
void gemm_kernel(const float* __restrict__ A, const float* __restrict__ B,
                 float* __restrict__ C, const float* __restrict__ bias,
                 int M, int K, int N)
{
    int m0 = blockIdx.y * 64;
    int n0 = blockIdx.x * 64;
    __shared__ float As[16][65];
    __shared__ float Bs[16][64];
    int tid = threadIdx.x;
    int tx = tid & 15, ty = tid >> 4;
    float acc[4][4] = {};
    for (int k0 = 0; k0 < K; k0 += 16) {
        #pragma unroll
        for (int e = 0; e < 4; e++) {
            int idx = tid + e * 256;
            int m = idx >> 4, k = idx & 15;
            float v = 0.f;
            if (k0 + k < K) v = A[(size_t)(m0 + m) * K + k0 + k];
            As[k][m] = v;
        }
        #pragma unroll
        for (int e = 0; e < 4; e++) {
            int idx = tid + e * 256;
            int k = idx >> 6, n = idx & 63;
            float v = 0.f;
            if (k0 + k < K) v = B[(size_t)(k0 + k) * N + n0 + n];
            Bs[k][n] = v;
        }
        __syncthreads();
        #pragma unroll
        for (int kk = 0; kk < 16; kk++) {
            float av[4], bv[4];
            #pragma unroll
            for (int i = 0; i < 4; i++) av[i] = As[kk][ty * 4 + i];
            #pragma unroll
            for (int j = 0; j < 4; j++) bv[j] = Bs[kk][tx * 4 + j];
            #pragma unroll
            for (int i = 0; i < 4; i++)
                #pragma unroll
                for (int j = 0; j < 4; j++)
                    acc[i][j] = fmaf(av[i], bv[j], acc[i][j]);
        }
        __syncthreads();
    }
    #pragma unroll
    for (int i = 0; i < 4; i++) {
        int m = m0 + ty * 4 + i;
        #pragma unroll
        for (int j = 0; j < 4; j++) {
            int n = n0 + tx * 4 + j;
            float v = acc[i][j];
            if (bias) v += bias[n];
            C[(size_t)m * N + n] = v;
        }
    }
}

// ---------------- split-bf16 MFMA GEMM ---------------------------------------
// C[z] = Ah@Bh^T + Ah@Bl^T + Al@Bh^T  (fp32 acc).  A: [M][K] bf16 (shared
// across z), B: [N][K] bf16 per z (pre-transposed), C: [M][N] fp32 per z.
// Tile 128x128, 4 waves, each wave = 64x64 quadrant of 4x4 16x16x32 mfmas.
// LDS cells (16B = 8 k-consecutive bf16) XOR-swizzled: cell(r,kg)=r*4+(kg^(r&3)).
__global__ __launch_bounds__(256)
void gemm_mfma_kernel(const __hip_bfloat16* __restrict__ Ah,
                      const __hip_bfloat16* __restrict__ Al,
                      const __hip_bfloat16* __restrict__ Bh,
                      const __hip_bfloat16* __restrict__ Bl,
                      float* __restrict__ C,
                      int M, int N, int K, long strideBz, long strideCz)
{
    int z = blockIdx.z;
    const __hip_bfloat16* bhz = Bh + (size_t)z * strideBz;
    const __hip_bfloat16* blz = Bl + (size_t)z * strideBz;
    float* Cz = C + (size_t)z * strideCz;
    int m0 = blockIdx.y * 128, n0 = blockIdx.x * 128;

    __shared__ __align__(16) unsigned short ls[4][4096];  // Ah, Al, Bh, Bl: 8KB each

    int tid = threadIdx.x, w = tid >> 6, lane = tid & 63;
    int qr = w >> 1, qc = w & 1;

    const __hip_bfloat16* gp;
    int o0;
    if      (w == 0) { gp = Ah;  o0 = m0; }
    else if (w == 1) { gp = Al;  o0 = m0; }
    else if (w == 2) { gp = bhz; o0 = n0; }
    else             { gp = blz; o0 = n0; }
    unsigned short* lbase = &ls[w][0];

    f32x4 acc[4][4];
    #pragma unroll
    for (int i = 0; i < 4; i++)
        #pragma unroll
        for (int j = 0; j < 4; j++)
            acc[i][j] = (f32x4){0.f, 0.f, 0.f, 0.f};

    for (int k0 = 0; k0 < K; k0 += 32) {
        __syncthreads();
        #pragma unroll
        for (int i = 0; i < 8; ++i) {              // stage this wave's array
            int c = i * 64 + lane;
            int row = c >> 2;
            int kg = (c & 3) ^ (row & 3);
            async_copy16(gp + (size_t)(o0 + row) * K + k0 + kg * 8,
                         lbase + (size_t)c * 8);
        }
        __syncthreads();

        s16x8 fa[2][4], fb[2][4];
        int kg = lane >> 4;
        #pragma unroll
        for (int tr = 0; tr < 4; ++tr) {
            int row = qr * 64 + tr * 16 + (lane & 15);
            int cell = row * 4 + (kg ^ (row & 3));
            fa[0][tr] = *(const s16x8*)&ls[0][cell * 8];
            fa[1][tr] = *(const s16x8*)&ls[1][cell * 8];
        }
        #pragma unroll
        for (int tc = 0; tc < 4; ++tc) {
            int nn = qc * 64 + tc * 16 + (lane & 15);
            int cell = nn * 4 + (kg ^ (nn & 3));
            fb[0][tc] = *(const s16x8*)&ls[2][cell * 8];
            fb[1][tc] = *(const s16x8*)&ls[3][cell * 8];
        }
        #pragma unroll
        for (int tr = 0; tr < 4; ++tr)
            #pragma unroll
            for (int tc = 0; tc < 4; ++tc) {
                acc[tr][tc] = __builtin_amdgcn_mfma_f32_16x16x32_bf16(
                    fa[0][tr], fb[0][tc], acc[tr][tc], 0, 0, 0);
                acc[tr][tc] = __builtin_amdgcn_mfma_f32_16x16x32_bf16(
                    fa[0][tr], fb[1][tc], acc[tr][tc], 0, 0, 0);
                acc[tr][tc] = __builtin_amdgcn_mfma_f32_16x16x32_bf16(
                    fa[1][tr], fb[0][tc], acc[tr][tc], 0, 0, 0);
            }
    }
    // epilogue: C/D layout col=lane&15, row=(lane>>4)*4+reg  [m89-verified]
    #pragma unroll
    for (int tr = 0; tr < 4; ++tr) {
        int rbase = m0 + qr * 64 + tr * 16 + (lane >> 4) * 4;
        #pragma unroll
        for (int tc = 0; tc < 4; ++tc) {
            int col = n0 + qc * 64 + tc * 16 + (lane & 15);
            #pragma unroll
            for (int r = 0; r < 4; ++r)
                Cz[(size_t)(rbase + r) * N + col] = acc[tr][tc][r];
        }
    }
}

// ---------------- f/g = Wh @ a1, Wh @ a2 (one wave per row) ------------------
__global__ __launch_bounds__(256)
void fg_kernel(const float* __restrict__ WhAll, const float* __restrict__ aAll,
               float* __restrict__ fAll, float* __restrict__ gAll,
               int R, long aStride)
{
    int h = blockIdx.y;
    int row = blockIdx.x * 4 + (threadIdx.x >> 6);
    int lane = threadIdx.x & 63;
    if (row >= R) return;
    const float* wh = WhAll + (size_t)h * R * 256 + (size_t)row * 256;
    const float* a = aAll + (size_t)h * aStride;
    float sf = 0.f, sg = 0.f;
    #pragma unroll
    for (int k = lane; k < 256; k += 64) {
        float v = wh[k];
        sf = fmaf(v, a[k], sf);
        sg = fmaf(v, a[256 + k], sg);
    }
    #pragma unroll
    for (int off = 32; off > 0; off >>= 1) {
        sf += __shfl_down(sf, off);
        sg += __shfl_down(sg, off);
    }
    if (lane == 0) {
        fAll[(size_t)h * R + row] = sf;
        gAll[(size_t)h * R + row] = sg;
    }
}

// ---------------- LDS-staged sparse attention --------------------------------
// grid (fc=16, t, h). Block stages Wh[t-frame rows][fc*16..+16] (512x16 fp32,
// padded stride 17) in LDS; 4 waves x 4 quarter-waves = 16 rows in flight;
// online softmax per row with shuffle broadcast; writes bf16 hi/lo outputs.
__global__ __launch_bounds__(256)
void attn_kernel(const float* __restrict__ WhAll, const float* __restrict__ fAll,
                 const float* __restrict__ gAll,
                 const int* __restrict__ nbr_cnt, const int* __restrict__ nbr_idx,
                 __hip_bfloat16* __restrict__ outHi, __hip_bfloat16* __restrict__ outLo,
                 int outStride, int headColStride, int R, int doubleElu)
{
    int fc = blockIdx.x;
    int t  = blockIdx.y;
    int h  = blockIdx.z;
    const float* Wh = WhAll + (size_t)h * R * 256;
    const float* f = fAll + (size_t)h * R;
    const float* g = gAll + (size_t)h * R;

    __shared__ float slab[512 * 17];   // padded: row stride 17 floats

    int tid = threadIdx.x;
    // stage 512 rows x 16 feats
    for (int it = 0; it < 8; ++it) {
        int idx = it * 256 + tid;              // 2048 float4 chunks
        int row = idx >> 2, fq = idx & 3;
        const float* src = &Wh[(size_t)(t * 512 + row) * 256 + fc * 16 + fq * 4];
        float4 v = *(const float4*)src;
        float* d = &slab[row * 17 + fq * 4];
        d[0] = v.x; d[1] = v.y; d[2] = v.z; d[3] = v.w;
    }
    __syncthreads();

    int w = tid >> 6, lane = tid & 63;
    int q = lane >> 4;          // quarter-wave: row slot
    int lj = lane & 15;         // feat / neighbor slot within quarter

    for (int step = 0; step < 32; ++step) {
        int i = step * 16 + w * 4 + q;       // node 0..511
        int c = nbr_cnt[i];
        float fi = f[t * 512 + i];

        float m = -1e30f, l = 0.f, acc = 0.f;
        for (int j0 = 0; j0 < c; j0 += 16) {
            int j = j0 + lj;
            bool ok = j < c;
            int id = ok ? nbr_idx[i * 512 + j] : 0;
            float e = -1e30f;
            if (ok) {
                float ee = fi + g[t * 512 + id];
                e = ee >= 0.f ? ee : 0.2f * ee;     // leaky_relu(0.2)
            }
            float cm = e;
            #pragma unroll
            for (int off = 1; off < 16; off <<= 1)
                cm = fmaxf(cm, __shfl_xor(cm, off, 16));
            float mn = fmaxf(m, cm);
            float p = ok ? __expf(e - mn) : 0.f;
            float cs = p;
            #pragma unroll
            for (int off = 1; off < 16; off <<= 1)
                cs += __shfl_xor(cs, off, 16);
            float scale = __expf(m - mn);
            l = l * scale + cs;
            acc *= scale;
            m = mn;
            int lim = c - j0; if (lim > 16) lim = 16;
            int src_base = lane & 48;                 // q*16
            for (int jj = 0; jj < lim; ++jj) {
                float pj = __shfl(p, src_base | jj);
                int  idj = __shfl(id, src_base | jj);
                acc = fmaf(pj, slab[idj * 17 + lj], acc);
            }
        }
        float v = acc / l;
        float o = v > 0.f ? v : expm1f(v);            // elu
        if (doubleElu) o = o > 0.f ? o : expm1f(o);   // outer elu
        size_t oidx = (size_t)(t * 512 + i) * outStride + h * headColStride + fc * 16 + lj;
        __hip_bfloat16 hi = __float2bfloat16(o);
        outHi[oidx] = hi;
        outLo[oidx] = __float2bfloat16(o - __bfloat162float(hi));
    }
}

// ---------------- pooling ----------------------------------------------------
__global__ __launch_bounds__(256)
void pool_partial_kernel(const __hip_bfloat16* __restrict__ xh,
                         const __hip_bfloat16* __restrict__ xl,
                         float* __restrict__ partial)
{
    int t = blockIdx.x, ch = blockIdx.y, c = threadIdx.x;
    float s = 0.f;
    for (int n = ch * 64; n < ch * 64 + 64; ++n) {
        size_t idx = (size_t)(t * 512 + n) * 256 + c;
        s += __bfloat162float(xh[idx]) + __bfloat162float(xl[idx]);
    }
    partial[(t * 8 + ch) * 256 + c] = s;
}

__global__ __launch_bounds__(256)
void final_kernel(const float* __restrict__ partial, const float* __restrict__ Wo,
                  const float* __restrict__ bo, float* __restrict__ out)
{
    int t = blockIdx.x, c = threadIdx.x;
    __shared__ float pooled[256];
    float s = 0.f;
    #pragma unroll
    for (int ch = 0; ch < 8; ch++) s += partial[(t * 8 + ch) * 256 + c];
    pooled[c] = s * (1.f / 512.f);
    __syncthreads();
    float o = bo[c];
    for (int k = 0; k < 256; k++) o = fmaf(pooled[k], Wo[k * 256 + c], o);
    out[t * 256 + c] = o;
}

extern "C" void kernel_launch(void* const* d_in, const int* in_sizes, int n_in,
                              void* d_out, int out_size, void* d_ws, size_t ws_size,
                              hipStream_t stream)
{
    const float* pose   = (const float*)d_in[0];   // [32,512,3]
    const int*   adj    = (const int*)  d_in[1];   // [512,512]
    const float* Wp     = (const float*)d_in[2];   // [3,256]
    const float* bp     = (const float*)d_in[3];   // [256]
    const float* Wh_w   = (const float*)d_in[4];   // [3,8,256,256]
    const float* a_h    = (const float*)d_in[5];   // [3,8,512]
    const float* W_outw = (const float*)d_in[6];   // [3,2048,256]
    const float* a_o    = (const float*)d_in[7];   // [3,512]
    const float* Wo     = (const float*)d_in[8];   // [256,256]
    const float* bo     = (const float*)d_in[9];   // [256]
    float* out = (float*)d_out;                    // [32,256]

    const int T = 32, N = 512, F = 256, H = 8, L = 3, Din = 3;

    auto align256 = [](size_t b) { return (b + 255) & ~(size_t)255; };
    auto need = [&](int TC) -> size_t {
        size_t R = (size_t)TC * N;
        size_t b = 0;
        b += align256((size_t)H * R * F * 4);        // WhAll (also proj temp)
        b += 2 * align256(R * (size_t)H * F * 2);    // xcat hi/lo
        b += 2 * align256(R * F * 2);                // x hi/lo
        b += 2 * align256((size_t)H * R * 4);        // f,g
        b += 4 * align256((size_t)L * H * F * F * 2);// weight hi/lo (heads+out)
        b += align256(512 * 4) + align256(512 * 512 * 4);
        b += align256((size_t)TC * 8 * F * 4);       // pool partials
        return b + 4096;
    };
    int TC = 32;
    while (TC > 1 && need(TC) > ws_size) TC >>= 1;
    size_t R = (size_t)TC * N;

    char* wp = (char*)d_ws;
    auto alloc = [&](size_t bytes) -> char* {
        char* r = wp; wp += (bytes + 255) & ~(size_t)255; return r;
    };
    float*          whall  = (float*)alloc((size_t)H * R * F * 4);
    __hip_bfloat16* xcat_h = (__hip_bfloat16*)alloc(R * (size_t)H * F * 2);
    __hip_bfloat16* xcat_l = (__hip_bfloat16*)alloc(R * (size_t)H * F * 2);
    __hip_bfloat16* x_h    = (__hip_bfloat16*)alloc(R * F * 2);
    __hip_bfloat16* x_l    = (__hip_bfloat16*)alloc(R * F * 2);
    float*          fAll   = (float*)alloc((size_t)H * R * 4);
    float*          gAll   = (float*)alloc((size_t)H * R * 4);
    __hip_bfloat16* wth    = (__hip_bfloat16*)alloc((size_t)L * H * F * F * 2);
    __hip_bfloat16* wtl    = (__hip_bfloat16*)alloc((size_t)L * H * F * F * 2);
    __hip_bfloat16* woth   = (__hip_bfloat16*)alloc((size_t)L * H * F * F * 2);
    __hip_bfloat16* wotl   = (__hip_bfloat16*)alloc((size_t)L * H * F * F * 2);
    int*            ncnt   = (int*)alloc(512 * 4);
    int*            nidx   = (int*)alloc(512 * 512 * 4);
    float*          partial= (float*)alloc((size_t)TC * 8 * F * 4);

    build_csr_kernel<<<128, 256, 0, stream>>>(adj, ncnt, nidx);
    // weights: [b][K][N] -> [b][N][K] bf16 hi/lo
    transpose_split_kernel<<<dim3(F / 32, F / 32, L * H), 256, 0, stream>>>(
        Wh_w, wth, wtl, F, F);
    transpose_split_kernel<<<dim3(F / 32, (H * F) / 32, L), 256, 0, stream>>>(
        W_outw, woth, wotl, H * F, F);

    for (int t0 = 0; t0 < T; t0 += TC) {
        // input projection (fp32, K=3): whall used as temp x
        gemm_kernel<<<dim3(F / 64, (unsigned)(R / 64)), 256, 0, stream>>>(
            pose + (size_t)t0 * N * Din, Wp, whall, bp, (int)R, Din, F);
        split_kernel<<<(unsigned)(R * F / 256), 256, 0, stream>>>(
            whall, x_h, x_l, (int)(R * F));

        for (int l = 0; l < L; l++) {
            // Wh[h] = x @ W_heads[l,h]  (z-batched over heads)
            gemm_mfma_kernel<<<dim3(F / 128, (unsigned)(R / 128), H), 256, 0, stream>>>(
                x_h, x_l,
                wth + (size_t)l * H * F * F, wtl + (size_t)l * H * F * F,
                whall, (int)R, F, F, (long)F * F, (long)R * F);
            fg_kernel<<<dim3((unsigned)(R / 4), H), 256, 0, stream>>>(
                whall, a_h + (size_t)l * H * 2 * F, fAll, gAll, (int)R, 2 * F);
            attn_kernel<<<dim3(16, TC, H), 256, 0, stream>>>(
                whall, fAll, gAll, ncnt, nidx, xcat_h, xcat_l,
                H * F, F, (int)R, 0);
            // out-gat: WhO = xcat @ W_out[l]   (K = 2048)
            gemm_mfma_kernel<<<dim3(F / 128, (unsigned)(R / 128), 1), 256, 0, stream>>>(
                xcat_h, xcat_l,
                woth + (size_t)l * H * F * F, wotl + (size_t)l * H * F * F,
                whall, (int)R, F, H * F, 0, 0);
            fg_kernel<<<dim3((unsigned)(R / 4), 1), 256, 0, stream>>>(
                whall, a_o + (size_t)l * 2 * F, fAll, gAll, (int)R, 2 * F);
            attn_kernel<<<dim3(16, TC, 1), 256, 0, stream>>>(
                whall, fAll, gAll, ncnt, nidx, x_h, x_l,
                F, 0, (int)R, 1);
        }
        pool_partial_kernel<<<dim3(TC, 8), 256, 0, stream>>>(x_h, x_l, partial);
        final_kernel<<<TC, 256, 0, stream>>>(partial, Wo, bo, out + (size_t)t0 * F);
    }
}